// Round 2
// baseline (3168.259 us; speedup 1.0000x reference)
//
#include <hip/hip_runtime.h>

// Persistent single-kernel implementation with runtime dtype detection.
// B=1; 20 sequential steps of: MLP(1024->256->128->64) -> gumbel softmax ->
// A = sum_t soft[t]*Omega_t -> v_new = expm(A) @ v via Taylor matvecs
// (||A|| <~ 0.45 so 5 terms converge to ~1e-7).
// Grid-wide phases separated by a self-resetting device barrier.
//
// Round-1 NaN post-mortem: reading f32 inputs as packed bf16 makes mantissa
// halves into random exponents (Inf/NaN among 16.7M omega elems). This
// version detects bf16-vs-f32 from v_src's bit patterns and specializes.

#define NBLK 256
#define NTHR 256
#define NSTEP 20
#define NTAY 5
#define MAXBAR 160

__device__ int g_arrive[MAXBAR];  // zero-initialized at module load
__device__ int g_leave[MAXBAR];

__device__ __forceinline__ float b2f(unsigned short u) {
  union { unsigned int i; float f; } v; v.i = ((unsigned int)u) << 16; return v.f;
}
__device__ __forceinline__ unsigned short f2b(float f) {
  unsigned int x = __float_as_uint(f);
  unsigned int r = (x + 0x7FFFu + ((x >> 16) & 1u)) >> 16;
  return (unsigned short)r;
}

// Grid barrier: arrive + leave counters per slot; last leaver resets both so
// graph replays start clean. Device-scope fences for cross-XCD visibility.
__device__ __forceinline__ void gbar(int idx) {
  __syncthreads();
  if (threadIdx.x == 0) {
    __threadfence();
    __hip_atomic_fetch_add(&g_arrive[idx], 1, __ATOMIC_RELAXED, __HIP_MEMORY_SCOPE_AGENT);
    while (__hip_atomic_load(&g_arrive[idx], __ATOMIC_RELAXED, __HIP_MEMORY_SCOPE_AGENT) < NBLK)
      __builtin_amdgcn_s_sleep(2);
    __threadfence();
    int lv = __hip_atomic_fetch_add(&g_leave[idx], 1, __ATOMIC_RELAXED, __HIP_MEMORY_SCOPE_AGENT);
    if (lv == NBLK - 1) {
      __hip_atomic_store(&g_arrive[idx], 0, __ATOMIC_RELAXED, __HIP_MEMORY_SCOPE_AGENT);
      __hip_atomic_store(&g_leave[idx], 0, __ATOMIC_RELAXED, __HIP_MEMORY_SCOPE_AGENT);
    }
  }
  __syncthreads();
}

__device__ __forceinline__ float wredsum(float p) {
#pragma unroll
  for (int off = 32; off > 0; off >>= 1) p += __shfl_xor(p, off, 64);
  return p;
}

template <int ISF>
__device__ __forceinline__ float ld(const void* p, int i) {
  if (ISF) return ((const float*)p)[i];
  return b2f(((const unsigned short*)p)[i]);
}
template <int ISF>
__device__ __forceinline__ void st(void* p, int i, float v) {
  if (ISF) ((float*)p)[i] = v;
  else ((unsigned short*)p)[i] = f2b(v);
}
template <int ISF>
__device__ __forceinline__ float4 ld4(const void* p, long long i) {
  if (ISF) return *(const float4*)((const float*)p + i);
  ushort4 t = *(const ushort4*)((const unsigned short*)p + i);
  return make_float4(b2f(t.x), b2f(t.y), b2f(t.z), b2f(t.w));
}

// ws float layout:
// [0..511] vbuf0 | [512..1023] vbuf1 | [1024..1535] v_target f32
// [1536..2047] vnew | [2048..2559] wbufA | [2560..3071] wbufB
// [3072..3327] h1 | [3328..3391] soft | ints @3392: done_par0, done_par1, tgt_idx

template <int ISF>
__device__ void body(const void* vsrc, const void* vtgt, const void* omg,
                     const void* W1, const void* b1, const void* W2,
                     const void* b2, const void* W3, const void* b3,
                     const void* gum, float* __restrict__ F, void* out) {
  __shared__ float A_s[1024];
  __shared__ float w_s[512];
  __shared__ float soft_s[64];
  __shared__ float redf[256];
  __shared__ int   redi[256];
  __shared__ float h2_s[128];
  __shared__ float4 red4[4];
  __shared__ int   ibc[1];

  const int b = blockIdx.x;
  const int tid = threadIdx.x;

  float* vb0 = F;         float* vb1 = F + 512;
  float* tgtf = F + 1024; float* vnew = F + 1536;
  float* wbA = F + 2048;  float* wbB = F + 2560;
  float* h1g = F + 3072;  float* softg = F + 3328;
  int*   Iw  = (int*)(F + 3392);

  int bi = 0;

  if (b == 0) {
    float bv = -1e30f; int bidx = 0;
    for (int i = tid; i < 512; i += NTHR) {
      float tv = ld<ISF>(vtgt, i);
      tgtf[i] = tv;
      vb0[i]  = ld<ISF>(vsrc, i);
      if (tv > bv) { bv = tv; bidx = i; }
    }
    redf[tid] = bv; redi[tid] = bidx;
    __syncthreads();
    for (int off = 128; off > 0; off >>= 1) {
      if (tid < off) {
        float ov = redf[tid + off]; int oi = redi[tid + off];
        if (ov > redf[tid] || (ov == redf[tid] && oi < redi[tid])) { redf[tid] = ov; redi[tid] = oi; }
      }
      __syncthreads();
    }
    if (tid == 0) { Iw[0] = 0; Iw[2] = redi[0]; }
  }
  gbar(bi++);

  float accv = 0.0f;

  for (int s = 0; s < NSTEP; ++s) {
    const int cp = s & 1;
    const int pp = (s - 1) & 1;
    float* vcur = cp ? vb1 : vb0;
    float* vold = (s == 0) ? vb0 : (pp ? vb1 : vb0);

    // ---- P1: done update + freeze + MLP layer 1 (blocks 0..63) ----
    if (b < 64) {
      const int done_prev = (s == 0) ? 0 : Iw[pp];
      int done_cur;
      if (s == 0) {
        done_cur = 0;
      } else if (done_prev) {
        done_cur = 1;
      } else {
        float bv = -1e30f; int bidx = 0;
        for (int i = tid; i < 512; i += NTHR) {
          float vv = vnew[i];
          if (vv > bv) { bv = vv; bidx = i; }
        }
        redf[tid] = bv; redi[tid] = bidx;
        __syncthreads();
        for (int off = 128; off > 0; off >>= 1) {
          if (tid < off) {
            float ov = redf[tid + off]; int oi = redi[tid + off];
            if (ov > redf[tid] || (ov == redf[tid] && oi < redi[tid])) { redf[tid] = ov; redi[tid] = oi; }
          }
          __syncthreads();
        }
        if (tid == 0) ibc[0] = (redi[0] == Iw[2]) ? 1 : 0;
        __syncthreads();
        done_cur = ibc[0];
      }
      if (b == 0) {
        if (s > 0) {
          for (int i = tid; i < 512; i += NTHR)
            vcur[i] = done_prev ? vold[i] : vnew[i];
        }
        if (tid == 0) Iw[cp] = done_cur;
      }
      if (!done_cur) {
        float p0 = 0, p1 = 0, p2 = 0, p3 = 0;
#pragma unroll
        for (int k = 0; k < 4; ++k) {
          const int i = tid + (k << 8);
          float xi;
          if (i < 512) xi = (s == 0) ? vold[i] : (done_prev ? vold[i] : vnew[i]);
          else         xi = tgtf[i - 512];
          const float4 wv = ld4<ISF>(W1, (long long)i * 256 + (b << 2));
          p0 = fmaf(xi, wv.x, p0);
          p1 = fmaf(xi, wv.y, p1);
          p2 = fmaf(xi, wv.z, p2);
          p3 = fmaf(xi, wv.w, p3);
        }
        p0 = wredsum(p0); p1 = wredsum(p1); p2 = wredsum(p2); p3 = wredsum(p3);
        if ((tid & 63) == 0) red4[tid >> 6] = make_float4(p0, p1, p2, p3);
        __syncthreads();
        if (tid == 0) {
          float s0 = red4[0].x + red4[1].x + red4[2].x + red4[3].x + ld<ISF>(b1, (b << 2) + 0);
          float s1 = red4[0].y + red4[1].y + red4[2].y + red4[3].y + ld<ISF>(b1, (b << 2) + 1);
          float s2 = red4[0].z + red4[1].z + red4[2].z + red4[3].z + ld<ISF>(b1, (b << 2) + 2);
          float s3 = red4[0].w + red4[1].w + red4[2].w + red4[3].w + ld<ISF>(b1, (b << 2) + 3);
          h1g[(b << 2) + 0] = fmaxf(s0, 0.f);
          h1g[(b << 2) + 1] = fmaxf(s1, 0.f);
          h1g[(b << 2) + 2] = fmaxf(s2, 0.f);
          h1g[(b << 2) + 3] = fmaxf(s3, 0.f);
        }
      }
    }
    gbar(bi++);

    // ---- P2: block 0: layers 2,3 + softmax + logits output ----
    if (b == 0) {
      const int dc = Iw[cp];
      if (!dc) {
        redf[tid] = h1g[tid];
        __syncthreads();
        float hh = 0.f;
        if (tid < 128) {
          float a = ld<ISF>(b2, tid);
#pragma unroll 8
          for (int i = 0; i < 256; ++i) a = fmaf(redf[i], ld<ISF>(W2, i * 128 + tid), a);
          hh = fmaxf(a, 0.f);
        }
        __syncthreads();
        if (tid < 128) h2_s[tid] = hh;
        __syncthreads();
        if (tid < 64) {
          float a = ld<ISF>(b3, tid);
#pragma unroll 8
          for (int i = 0; i < 128; ++i) a = fmaf(h2_s[i], ld<ISF>(W3, i * 64 + tid), a);
          float lg = a + ld<ISF>(gum, s * 64 + tid);  // TAU = 1
          float mx = lg;
#pragma unroll
          for (int off = 32; off > 0; off >>= 1) mx = fmaxf(mx, __shfl_xor(mx, off, 64));
          float e = __expf(lg - mx);
          float sm = e;
#pragma unroll
          for (int off = 32; off > 0; off >>= 1) sm += __shfl_xor(sm, off, 64);
          softg[tid] = e / sm;
          st<ISF>(out, 512 + s * 64 + tid, a);  // pre-gumbel logits
        }
      } else {
        if (tid < 64) st<ISF>(out, 512 + s * 64 + tid, 0.0f);
      }
    }
    gbar(bi++);

    // ---- P3: mix 2 rows of A into LDS + Taylor n=1 (all blocks) ----
    const int done_cur = Iw[cp];
    if (!done_cur) {
      if (tid < 64) soft_s[tid] = softg[tid];
      w_s[tid] = vcur[tid];
      w_s[tid + 256] = vcur[tid + 256];
      __syncthreads();
      {
        const int idx = tid << 2;
        const long long base = ((long long)b << 10) + idx;
        float a0 = 0, a1 = 0, a2 = 0, a3 = 0;
#pragma unroll 8
        for (int t = 0; t < 64; ++t) {
          const float4 ov = ld4<ISF>(omg, base + (long long)t * 262144);
          const float sv = soft_s[t];
          a0 = fmaf(sv, ov.x, a0);
          a1 = fmaf(sv, ov.y, a1);
          a2 = fmaf(sv, ov.z, a2);
          a3 = fmaf(sv, ov.w, a3);
        }
        A_s[idx + 0] = a0; A_s[idx + 1] = a1; A_s[idx + 2] = a2; A_s[idx + 3] = a3;
      }
      __syncthreads();
      {
        const int wv_id = tid >> 6, ln = tid & 63;
        if (wv_id < 2) {
          const float* Ar = A_s + (wv_id << 9);
          float p = 0.f;
#pragma unroll
          for (int k = 0; k < 8; ++k) p = fmaf(Ar[ln + (k << 6)], w_s[ln + (k << 6)], p);
          p = wredsum(p);
          if (ln == 0) {
            accv = w_s[(b << 1) + wv_id] + p;
            wbB[(b << 1) + wv_id] = p;
          }
        }
      }
    }
    gbar(bi++);

    // ---- Taylor n = 2..NTAY ----
    for (int n = 2; n <= NTAY; ++n) {
      if (!done_cur) {
        const float* wsrc = ((n - 1) & 1) ? wbB : wbA;
        w_s[tid] = wsrc[tid];
        w_s[tid + 256] = wsrc[tid + 256];
        __syncthreads();
        const int wv_id = tid >> 6, ln = tid & 63;
        if (wv_id < 2) {
          const float* Ar = A_s + (wv_id << 9);
          float p = 0.f;
#pragma unroll
          for (int k = 0; k < 8; ++k) p = fmaf(Ar[ln + (k << 6)], w_s[ln + (k << 6)], p);
          p = wredsum(p) * (1.0f / (float)n);
          if (ln == 0) {
            accv += p;
            float* wdst = (n & 1) ? wbB : wbA;
            wdst[(b << 1) + wv_id] = p;
            if (n == NTAY) vnew[(b << 1) + wv_id] = accv;
          }
        }
      }
      gbar(bi++);
    }
  }

  // ---- epilogue ----
  if (b == 0) {
    const int done19 = Iw[(NSTEP - 1) & 1];
    const float* v19 = ((NSTEP - 1) & 1) ? vb1 : vb0;
    for (int i = tid; i < 512; i += NTHR) {
      float vf = done19 ? v19[i] : vnew[i];
      st<ISF>(out, i, vf);
    }
  }
}

__global__ __launch_bounds__(NTHR) void petri_kernel(
    const void* vsrc, const void* vtgt, const void* omg, const void* W1,
    const void* b1, const void* W2, const void* b2, const void* W3,
    const void* b3, const void* gum, float* __restrict__ F, void* out) {
  // Runtime dtype detection: every block inspects v_src's even 16-bit halves.
  // bf16 data -> sane exponents everywhere (~N(0,1)); f32 data -> those are
  // mantissa bits, uniform. Deterministic & identical across blocks.
  __shared__ int dcount;
  if (threadIdx.x == 0) dcount = 0;
  __syncthreads();
  if (threadIdx.x < 128) {
    unsigned short u = ((const unsigned short*)vsrc)[threadIdx.x << 1];
    int e = (u >> 7) & 0xFF;
    if (e >= 64 && e <= 191) atomicAdd(&dcount, 1);
  }
  __syncthreads();
  if (dcount >= 96)
    body<0>(vsrc, vtgt, omg, W1, b1, W2, b2, W3, b3, gum, F, out);  // bf16
  else
    body<1>(vsrc, vtgt, omg, W1, b1, W2, b2, W3, b3, gum, F, out);  // f32
}

extern "C" void kernel_launch(void* const* d_in, const int* in_sizes, int n_in,
                              void* d_out, int out_size, void* d_ws, size_t ws_size,
                              hipStream_t stream) {
  (void)in_sizes; (void)n_in; (void)out_size; (void)ws_size;
  petri_kernel<<<dim3(NBLK), dim3(NTHR), 0, stream>>>(
      d_in[0], d_in[1], d_in[2], d_in[3], d_in[4], d_in[5], d_in[6], d_in[7],
      d_in[8], d_in[9], (float*)d_ws, d_out);
}

// Round 3
// 1303.858 us; speedup vs baseline: 2.4299x; 2.4299x over previous
//
#include <hip/hip_runtime.h>

// Persistent 64-block kernel, f32 I/O (proven in round 2).
// Per step: every block redundantly computes done/freeze + 4 h1 outputs;
// block 0 does MLP layers 2/3 + softmax; each block mixes its own 8 rows of
// A = sum_t soft_t * Omega_t into LDS and runs 5 Taylor matvec terms of
// expm(A)@v, exchanging only the 512-vector w between terms.
// All syncs are 64-wide ticket barriers (1 atomic/block/slot, monotonic,
// no reset -> safe across graph replays even with skipped (done) steps).

#define NBLK 64
#define NTHR 512
#define NSTEP 20
#define NTAY 5
#define NSLOT (NSTEP * 7)

__device__ int g_cnt[NSLOT];  // zero-init at module load; monotonic forever

__device__ __forceinline__ void gbar(int slot) {
  __syncthreads();
  if (threadIdx.x == 0) {
    __threadfence();  // release (compiler also drains vmcnt before barrier)
    int t = __hip_atomic_fetch_add(&g_cnt[slot], 1, __ATOMIC_RELAXED,
                                   __HIP_MEMORY_SCOPE_AGENT) + 1;
    const int target = ((t + NBLK - 1) / NBLK) * NBLK;
    while (__hip_atomic_load(&g_cnt[slot], __ATOMIC_RELAXED,
                             __HIP_MEMORY_SCOPE_AGENT) < target)
      __builtin_amdgcn_s_sleep(4);
    __threadfence();  // acquire: invalidate L1 for the whole CU
  }
  __syncthreads();
}

__device__ __forceinline__ float wredsum(float p) {
#pragma unroll
  for (int off = 32; off > 0; off >>= 1) p += __shfl_xor(p, off, 64);
  return p;
}

// ws (f32): h1g[256] @0 | softg[64] @256 | wb0[512] @320 | wb1[512] @832
//           | vng[512] @1344

__global__ __launch_bounds__(NTHR) void petri_kernel(
    const float* __restrict__ vsrc, const float* __restrict__ vtgt,
    const float* __restrict__ omg,  const float* __restrict__ W1,
    const float* __restrict__ b1,   const float* __restrict__ W2,
    const float* __restrict__ b2,   const float* __restrict__ W3,
    const float* __restrict__ b3,   const float* __restrict__ gum,
    float* __restrict__ F, float* __restrict__ out) {
  __shared__ float A_s[8 * 512];   // this block's 8 rows of A
  __shared__ float v_loc[512];     // current v (frozen-updated), per block
  __shared__ float tgt_s[512];
  __shared__ float w_s[512];
  __shared__ float soft_s[64];
  __shared__ float h1_s[256];
  __shared__ float h2_s[128];
  __shared__ float redf[512];
  __shared__ int   redi[512];
  __shared__ float4 red4[8];

  const int b = blockIdx.x;
  const int tid = threadIdx.x;
  const int wv = tid >> 6, ln = tid & 63;

  float* h1g  = F;
  float* softg = F + 256;
  float* wb0  = F + 320;
  float* wb1  = F + 832;
  float* vng  = F + 1344;

  // ---- prologue: local copies + target argmax (all blocks, redundant) ----
  {
    float tv = vtgt[tid];
    tgt_s[tid] = tv;
    v_loc[tid] = vsrc[tid];
    redf[tid] = tv; redi[tid] = tid;
    __syncthreads();
    for (int off = 256; off > 0; off >>= 1) {
      if (tid < off) {
        float ov = redf[tid + off]; int oi = redi[tid + off];
        if (ov > redf[tid] || (ov == redf[tid] && oi < redi[tid])) {
          redf[tid] = ov; redi[tid] = oi;
        }
      }
      __syncthreads();
    }
  }
  const int tgtIdx = redi[0];
  __syncthreads();

  int d = 0;          // done flag, bit-identical across blocks
  float accv = 0.0f;  // Taylor accumulator (lane 0 of each wave)

  for (int s = 0; s < NSTEP; ++s) {
    // ---- carry update: v_s = d ? v : vnew ; d |= argmax(vnew)==tgt ----
    if (s > 0 && !d) {
      float nv = vng[tid];   // visible via previous step-end barrier
      v_loc[tid] = nv;
      redf[tid] = nv; redi[tid] = tid;
      __syncthreads();
      for (int off = 256; off > 0; off >>= 1) {
        if (tid < off) {
          float ov = redf[tid + off]; int oi = redi[tid + off];
          if (ov > redf[tid] || (ov == redf[tid] && oi < redi[tid])) {
            redf[tid] = ov; redi[tid] = oi;
          }
        }
        __syncthreads();
      }
      if (redi[0] == tgtIdx) d = 1;
      __syncthreads();
    }

    const int base = s * 7;
    if (d) {  // frozen: zero logits row, skip all barriers (uniform)
      if (b == 0 && tid < 64) out[512 + s * 64 + tid] = 0.0f;
      continue;
    }

    // ---- L1: this block computes h1[4b..4b+3] ----
    {
      float p0 = 0, p1 = 0, p2 = 0, p3 = 0;
#pragma unroll
      for (int k = 0; k < 2; ++k) {
        const int i = tid + (k << 9);
        const float xi = (k == 0) ? v_loc[i] : tgt_s[i - 512];
        const float4 w4 = *(const float4*)(W1 + i * 256 + (b << 2));
        p0 = fmaf(xi, w4.x, p0); p1 = fmaf(xi, w4.y, p1);
        p2 = fmaf(xi, w4.z, p2); p3 = fmaf(xi, w4.w, p3);
      }
      p0 = wredsum(p0); p1 = wredsum(p1); p2 = wredsum(p2); p3 = wredsum(p3);
      if (ln == 0) red4[wv] = make_float4(p0, p1, p2, p3);
      __syncthreads();
      if (tid == 0) {
        float s0 = b1[(b << 2) + 0], s1 = b1[(b << 2) + 1];
        float s2 = b1[(b << 2) + 2], s3 = b1[(b << 2) + 3];
#pragma unroll
        for (int q = 0; q < 8; ++q) {
          s0 += red4[q].x; s1 += red4[q].y; s2 += red4[q].z; s3 += red4[q].w;
        }
        h1g[(b << 2) + 0] = fmaxf(s0, 0.f);
        h1g[(b << 2) + 1] = fmaxf(s1, 0.f);
        h1g[(b << 2) + 2] = fmaxf(s2, 0.f);
        h1g[(b << 2) + 3] = fmaxf(s3, 0.f);
      }
    }
    gbar(base + 0);

    // ---- block 0: layers 2,3 + softmax + logits output ----
    if (b == 0) {
      if (tid < 256) h1_s[tid] = h1g[tid];
      __syncthreads();
      if (tid < 128) {
        float a = b2[tid];
#pragma unroll 8
        for (int i = 0; i < 256; ++i) a = fmaf(h1_s[i], W2[i * 128 + tid], a);
        h2_s[tid] = fmaxf(a, 0.f);
      }
      __syncthreads();
      if (tid < 64) {
        float a = b3[tid];
#pragma unroll 8
        for (int i = 0; i < 128; ++i) a = fmaf(h2_s[i], W3[i * 64 + tid], a);
        float lg = a + gum[s * 64 + tid];  // TAU = 1
        float mx = lg;
#pragma unroll
        for (int off = 32; off > 0; off >>= 1) mx = fmaxf(mx, __shfl_xor(mx, off, 64));
        float e = __expf(lg - mx);
        float sm = e;
#pragma unroll
        for (int off = 32; off > 0; off >>= 1) sm += __shfl_xor(sm, off, 64);
        softg[tid] = e / sm;
        out[512 + s * 64 + tid] = a;  // pre-gumbel logits
      }
    }
    gbar(base + 1);  // soft ready (block 0 arrives after publishing)

    // ---- mix this block's 8 rows of A into LDS ----
    if (tid < 64) soft_s[tid] = softg[tid];
    __syncthreads();
    {
      const float* bp = omg + (b << 12);  // rows 8b.. : b*8*512 floats
      float a0 = 0, a1 = 0, a2 = 0, a3 = 0, a4 = 0, a5 = 0, a6 = 0, a7 = 0;
#pragma unroll 4
      for (int t = 0; t < 64; ++t) {
        const float* tp = bp + t * 262144;
        const float4 o1 = *(const float4*)(tp + (tid << 2));
        const float4 o2 = *(const float4*)(tp + 2048 + (tid << 2));
        const float sv = soft_s[t];
        a0 = fmaf(sv, o1.x, a0); a1 = fmaf(sv, o1.y, a1);
        a2 = fmaf(sv, o1.z, a2); a3 = fmaf(sv, o1.w, a3);
        a4 = fmaf(sv, o2.x, a4); a5 = fmaf(sv, o2.y, a5);
        a6 = fmaf(sv, o2.z, a6); a7 = fmaf(sv, o2.w, a7);
      }
      *(float4*)(A_s + (tid << 2)) = make_float4(a0, a1, a2, a3);
      *(float4*)(A_s + 2048 + (tid << 2)) = make_float4(a4, a5, a6, a7);
    }
    __syncthreads();

    // ---- w1 = A v (wave wv owns row wv of this block's 8) ----
    {
      const float* Ar = A_s + (wv << 9);
      float p = 0.f;
#pragma unroll
      for (int k = 0; k < 8; ++k) p = fmaf(Ar[ln + (k << 6)], v_loc[ln + (k << 6)], p);
      p = wredsum(p);
      if (ln == 0) {
        accv = v_loc[(b << 3) + wv] + p;  // w0 + w1
        wb1[(b << 3) + wv] = p;
      }
    }
    gbar(base + 2);

    // ---- Taylor n = 2..5 ; last barrier doubles as step-end ----
    for (int n = 2; n <= NTAY; ++n) {
      const float* wsrc = ((n - 1) & 1) ? wb1 : wb0;
      w_s[tid] = wsrc[tid];
      __syncthreads();
      const float* Ar = A_s + (wv << 9);
      float p = 0.f;
#pragma unroll
      for (int k = 0; k < 8; ++k) p = fmaf(Ar[ln + (k << 6)], w_s[ln + (k << 6)], p);
      p = wredsum(p) * (1.0f / (float)n);
      if (ln == 0) {
        accv += p;
        if (n < NTAY) {
          float* wd = (n & 1) ? wb1 : wb0;
          wd[(b << 3) + wv] = p;
        } else {
          vng[(b << 3) + wv] = accv;  // vnew
        }
      }
      gbar(base + 2 + (n - 1));  // n=2->+3 ... n=5->+6 (step-end)
    }
  }

  // ---- epilogue: v_final = d ? v_frozen : vnew_19 ----
  if (b == 0) {
    out[tid] = d ? v_loc[tid] : vng[tid];
  }
}

extern "C" void kernel_launch(void* const* d_in, const int* in_sizes, int n_in,
                              void* d_out, int out_size, void* d_ws, size_t ws_size,
                              hipStream_t stream) {
  (void)in_sizes; (void)n_in; (void)out_size; (void)ws_size;
  petri_kernel<<<dim3(NBLK), dim3(NTHR), 0, stream>>>(
      (const float*)d_in[0], (const float*)d_in[1], (const float*)d_in[2],
      (const float*)d_in[3], (const float*)d_in[4], (const float*)d_in[5],
      (const float*)d_in[6], (const float*)d_in[7], (const float*)d_in[8],
      (const float*)d_in[9], (float*)d_ws, (float*)d_out);
}